// Round 4
// baseline (648.744 us; speedup 1.0000x reference)
//
#include <hip/hip_runtime.h>
#include <stdint.h>

#define N_ATOMS 500000
#define N_MOLS  25000
#define HID     300
#define BA      128       // atoms per block
#define WS_ELE  102400    // elements per repacked W matrix (20*10*64*8)

// LDS layout (bytes)
#define NK16    19                // k16 chunks with real data (k<304)
#define A_BYTES (NK16 * 4096)     // A frags: [k16:19][rg:4][lane:64][16B] = 77824
#define B_OFF   A_BYTES
#define BUF_B   40960             // one K=32 B chunk: [mtx:2][h:2][nt:10][lane:64][16B]

typedef __attribute__((ext_vector_type(8)))  short          short8v;
typedef __attribute__((ext_vector_type(16))) float          f32x16;

static __device__ __forceinline__ unsigned short f2bf(float f) {
  unsigned int u = __float_as_uint(f);
  u += 0x7fffu + ((u >> 16) & 1u);   // round-to-nearest-even
  return (unsigned short)(u >> 16);
}

// async global->LDS, 16B per lane; lds base wave-uniform.
static __device__ __forceinline__ void stage16(const char* gsrc, char* ldst, int ln) {
  __builtin_amdgcn_global_load_lds(
      (const __attribute__((address_space(1))) void*)(gsrc + ln * 16),
      (__attribute__((address_space(3))) void*)ldst, 16, 0, 0);
}

// ---------------------------------------------------------------------------
// Prep: repack W1/V1 into B-fragment order [kc16:20][nt:10][lane:64][j:8]
// (k = kc16*16 + (lane>>5)*8 + j, n = nt*32 + (lane&31)), pad biases/readout
// vectors to 320, zero the segment-sum accumulators.
// ---------------------------------------------------------------------------
__global__ void prep_kernel(
    const float* __restrict__ W1, const float* __restrict__ V1,
    const float* __restrict__ b1, const float* __restrict__ vb1,
    const float* __restrict__ W2, const float* __restrict__ V2,
    unsigned short* __restrict__ W1s, unsigned short* __restrict__ V1s,
    float* __restrict__ b1p, float* __restrict__ vb1p,
    float* __restrict__ W2p, float* __restrict__ V2p,
    float* __restrict__ sums)
{
  const int t = blockIdx.x * 256 + threadIdx.x;
  if (t < 2 * WS_ELE) {
    const float* src = (t < WS_ELE) ? W1 : V1;
    unsigned short* dst = (t < WS_ELE) ? W1s : V1s;
    const int i    = (t < WS_ELE) ? t : t - WS_ELE;
    const int j    = i & 7;
    const int lane = (i >> 3) & 63;
    const int nt   = (i >> 9) % 10;
    const int kc16 = i / 5120;
    const int k = kc16 * 16 + (lane >> 5) * 8 + j;
    const int n = nt * 32 + (lane & 31);
    const float v = (k < HID && n < HID) ? src[k * HID + n] : 0.f;
    dst[i] = f2bf(v);
  } else if (t < 2 * WS_ELE + 1280) {
    const int i = t - 2 * WS_ELE;
    const int which = i / 320;
    const int e = i - which * 320;
    const float* s = (which == 0) ? b1 : (which == 1) ? vb1 : (which == 2) ? W2 : V2;
    float*       d = (which == 0) ? b1p : (which == 1) ? vb1p : (which == 2) ? W2p : V2p;
    d[e] = (e < HID) ? s[e] : 0.f;
  } else if (t < 2 * WS_ELE + 1280 + 2 * N_MOLS) {
    sums[t - (2 * WS_ELE + 1280)] = 0.f;
  }
}

// ---------------------------------------------------------------------------
// Fused FFN x2. Block = 128 atoms, 512 threads, 8 waves =
// {mtx:2} x {colhalf:2} x {rowhalf:2}; each wave computes 64 atoms x 160 cols
// of ONE matrix (acc = 2x5 f32x16 = 160 regs), so every B-frag LDS read feeds
// 2 MFMAs. A staged ONCE per block into LDS in fragment order (coalesced f32
// loads -> bf16). B double-buffered 2x40KB via global_load_lds, 2-phase:
// stage chunk c+1, compute chunk c, one barrier. 1 block/CU (160KB LDS);
// cross-CU phase stagger hides HBM.
// ---------------------------------------------------------------------------
__global__ __launch_bounds__(512, 2) void fused_ffn(
    const float* __restrict__ hidden,
    const unsigned short* __restrict__ W1s, const unsigned short* __restrict__ V1s,
    const float* __restrict__ b1p, const float* __restrict__ vb1p,
    const float* __restrict__ W2p, const float* __restrict__ V2p,
    const float* __restrict__ b2, const float* __restrict__ vb2,
    float* __restrict__ outA, float* __restrict__ outW)
{
  __shared__ char lds[A_BYTES + 2 * BUF_B];   // 159,744 B
  __shared__ float sOutA[BA];                 // +512
  __shared__ float sOutW[BA];                 // +512  -> 160,768 total

  const int tid = (int)threadIdx.x;
  const int ln  = tid & 63;
  const int wv  = tid >> 6;
  const int mtx = wv & 1;          // 0 = W-pass, 1 = V-pass
  const int ch  = (wv >> 1) & 1;   // col half (160 cols)
  const int rgh = wv >> 2;         // row half (64 atoms = rgs 2rgh, 2rgh+1)
  const int l31 = ln & 31;
  const int lh  = ln >> 5;
  const long base = (long)blockIdx.x * BA;

  // ---- issue B stage for chunk 0 into buf 0 (before A loads!) ----
  {
    char* dst = lds + B_OFF;
    #pragma unroll
    for (int r = 0; r < 5; ++r) {
      const int cc = wv * 5 + r;    // 40 x 1KB pieces: W = 0..19, V = 20..39
      const char* src = (cc < 20) ? ((const char*)W1s + cc * 1024)
                                  : ((const char*)V1s + (cc - 20) * 1024);
      stage16(src, dst + cc * 1024, ln);
    }
  }

  // ---- A: coalesced f32 loads (19 float4/thread, issued together) ----
  float4 ld[19];
  const bool tail = (tid >= 384);   // j=18 slot: tid<384 loads, tid>=384 pads
  #pragma unroll
  for (int j = 0; j < 19; ++j) {
    const int i = tid + j * 512;       // [0, 9728): row = i/75, c4 = i%75
    const int row = i / 75;
    const int c4  = i - row * 75;
    float4 v = make_float4(0.f, 0.f, 0.f, 0.f);
    const long atom = base + row;
    if ((j < 18 || !tail) && atom < N_ATOMS)
      v = *reinterpret_cast<const float4*>(hidden + atom * (long)HID + c4 * 4);
    ld[j] = v;
  }
  // ---- convert + ds_write into fragment order ----
  #pragma unroll
  for (int j = 0; j < 19; ++j) {
    if (j == 18 && tail) break;
    const int i   = tid + j * 512;
    const int row = i / 75;
    const int c4  = i - row * 75;
    const int k   = c4 * 4;
    const int k16 = k >> 4;
    const int sub = k & 15;            // 0,4,8,12
    ushort4 b;
    b.x = f2bf(ld[j].x); b.y = f2bf(ld[j].y);
    b.z = f2bf(ld[j].z); b.w = f2bf(ld[j].w);
    char* p = lds + k16 * 4096 + (row >> 5) * 1024
            + (((row & 31) + ((sub >> 3) << 5)) * 16) + (sub & 7) * 2;
    *reinterpret_cast<ushort4*>(p) = b;
  }
  if (tail) {
    // zero-pad k in [300,304): k16=18, sub=12 -> lane slot (row&31)+32, bytes 8..15
    const int row = tid - 384;         // 128 rows
    char* p = lds + 18 * 4096 + (row >> 5) * 1024 + (((row & 31) + 32) * 16) + 8;
    *reinterpret_cast<ushort4*>(p) = make_ushort4(0, 0, 0, 0);
  }
  __syncthreads();   // A staged; B chunk 0 landed (barrier drains vm+lgkm)

  f32x16 acc[2][5] = {};

  // ---- main loop: 10 chunks of K=32 (kc16 = 2c, 2c+1) ----
  for (int c = 0; c < 10; ++c) {
    const char* buf = lds + B_OFF + (c & 1) * BUF_B;

    if (c < 9) {   // stage chunk c+1 into the other buffer
      char* nbuf = lds + B_OFF + ((c + 1) & 1) * BUF_B;
      const char* wsrc = (const char*)W1s + (c + 1) * 20480;
      const char* vsrc = (const char*)V1s + (c + 1) * 20480;
      #pragma unroll
      for (int r = 0; r < 5; ++r) {
        const int cc = wv * 5 + r;
        const char* src = (cc < 20) ? (wsrc + cc * 1024) : (vsrc + (cc - 20) * 1024);
        stage16(src, nbuf + cc * 1024, ln);
      }
    }

    // compute chunk c: halves h=0,1 (skip h=1 at c=9: k>=304 is all pad)
#define DO_HALF(hh)                                                            \
    {                                                                          \
      const int kc16 = 2 * c + (hh);                                           \
      const short8v a0 = *reinterpret_cast<const short8v*>(                    \
          lds + kc16 * 4096 + (rgh * 2 + 0) * 1024 + ln * 16);                 \
      const short8v a1 = *reinterpret_cast<const short8v*>(                    \
          lds + kc16 * 4096 + (rgh * 2 + 1) * 1024 + ln * 16);                 \
      const char* bb = buf + mtx * 20480 + (hh) * 10240 + ch * 5120;           \
      _Pragma("unroll")                                                        \
      for (int nt = 0; nt < 5; ++nt) {                                         \
        const short8v bf = *reinterpret_cast<const short8v*>(                  \
            bb + nt * 1024 + ln * 16);                                         \
        acc[0][nt] = __builtin_amdgcn_mfma_f32_32x32x16_bf16(a0, bf, acc[0][nt], 0, 0, 0); \
        acc[1][nt] = __builtin_amdgcn_mfma_f32_32x32x16_bf16(a1, bf, acc[1][nt], 0, 0, 0); \
      }                                                                        \
    }
    DO_HALF(0);
    if (c < 9) DO_HALF(1);
#undef DO_HALF

    __syncthreads();
  }

  // ---- epilogue: out[atom] = sum_n relu(X+b1)*W2 + b2 ----
  float bv[5], w2[5];
  const float* bbv = mtx ? vb1p : b1p;
  const float* ww2 = mtx ? V2p  : W2p;
  #pragma unroll
  for (int nt = 0; nt < 5; ++nt) {
    const int cix = ch * 160 + nt * 32 + l31;
    bv[nt] = bbv[cix];
    w2[nt] = ww2[cix];
  }
  if (tid < BA) { sOutA[tid] = 0.f; sOutW[tid] = 0.f; }
  __syncthreads();

  float* sOut = mtx ? sOutW : sOutA;
  #pragma unroll
  for (int rg = 0; rg < 2; ++rg) {
    #pragma unroll
    for (int r = 0; r < 16; ++r) {
      float s = 0.f;
      #pragma unroll
      for (int nt = 0; nt < 5; ++nt) {
        float x = fmaxf(acc[rg][nt][r] + bv[nt], 0.f);
        s = fmaf(x, w2[nt], s);
      }
      s += __shfl_xor(s, 1);
      s += __shfl_xor(s, 2);
      s += __shfl_xor(s, 4);
      s += __shfl_xor(s, 8);
      s += __shfl_xor(s, 16);
      if (l31 == 0) {
        const int row = rgh * 64 + rg * 32 + (r & 3) + 8 * (r >> 2) + 4 * lh;
        atomicAdd(&sOut[row], s);
      }
    }
  }
  __syncthreads();
  if (tid < BA) {
    const long atom = base + tid;
    if (atom < N_ATOMS) {
      outA[atom] = sOutA[tid] + b2[0];
      outW[atom] = sOutW[tid] + vb2[0];
    }
  }
}

// ---------------------------------------------------------------------------
// Segment sums: sorted seg_ids, run-compress 8 atoms/thread before atomics.
// ---------------------------------------------------------------------------
__global__ void segsum_kernel(
    const float* __restrict__ outA, const float* __restrict__ outW,
    const int* __restrict__ seg,
    float* __restrict__ sum_o, float* __restrict__ sum_w)
{
  const long i0 = ((long)blockIdx.x * 256 + threadIdx.x) * 8;
  if (i0 >= N_ATOMS) return;
  const int4   s0 = *reinterpret_cast<const int4*>(seg + i0);
  const int4   s1 = *reinterpret_cast<const int4*>(seg + i0 + 4);
  const float4 o0 = *reinterpret_cast<const float4*>(outA + i0);
  const float4 o1 = *reinterpret_cast<const float4*>(outA + i0 + 4);
  const float4 w0 = *reinterpret_cast<const float4*>(outW + i0);
  const float4 w1 = *reinterpret_cast<const float4*>(outW + i0 + 4);
  const int   ss[8] = {s0.x, s0.y, s0.z, s0.w, s1.x, s1.y, s1.z, s1.w};
  const float oo[8] = {o0.x, o0.y, o0.z, o0.w, o1.x, o1.y, o1.z, o1.w};
  const float ww[8] = {w0.x, w0.y, w0.z, w0.w, w1.x, w1.y, w1.z, w1.w};
  int cur = ss[0];
  float ao = 0.f, aw = 0.f;
  #pragma unroll
  for (int j = 0; j < 8; ++j) {
    if (ss[j] != cur) {
      atomicAdd(&sum_o[cur], ao);
      atomicAdd(&sum_w[cur], aw);
      cur = ss[j]; ao = 0.f; aw = 0.f;
    }
    ao += oo[j]; aw += ww[j];
  }
  atomicAdd(&sum_o[cur], ao);
  atomicAdd(&sum_w[cur], aw);
}

// ---------------------------------------------------------------------------
// Final: out = output + weights * (0 - sum_o[seg]) / sum_w'[seg]
// ---------------------------------------------------------------------------
__global__ void final_kernel(
    const float* __restrict__ outA, const float* __restrict__ outW,
    const int* __restrict__ seg,
    const float* __restrict__ sum_o, const float* __restrict__ sum_w,
    float* __restrict__ out)
{
  const long i0 = ((long)blockIdx.x * 256 + threadIdx.x) * 4;
  if (i0 >= N_ATOMS) return;
  const int4   s4 = *reinterpret_cast<const int4*>(seg + i0);
  const float4 o4 = *reinterpret_cast<const float4*>(outA + i0);
  const float4 w4 = *reinterpret_cast<const float4*>(outW + i0);
  const int   ss[4] = {s4.x, s4.y, s4.z, s4.w};
  const float oo[4] = {o4.x, o4.y, o4.z, o4.w};
  const float ww[4] = {w4.x, w4.y, w4.z, w4.w};
  float r[4];
  #pragma unroll
  for (int j = 0; j < 4; ++j) {
    const int s = ss[j];
    float sw = sum_w[s];
    sw = (sw == 0.f) ? 1.f : sw;
    const float corr = (0.f - sum_o[s]) / sw;
    r[j] = oo[j] + ww[j] * corr;
  }
  *reinterpret_cast<float4*>(out + i0) = make_float4(r[0], r[1], r[2], r[3]);
}

// ---------------------------------------------------------------------------
extern "C" void kernel_launch(void* const* d_in, const int* in_sizes, int n_in,
                              void* d_out, int out_size, void* d_ws, size_t ws_size,
                              hipStream_t stream)
{
  const float* hidden = (const float*)d_in[0];
  const int*   seg    = (const int*)d_in[1];
  const float* W1     = (const float*)d_in[2];
  const float* b1     = (const float*)d_in[3];
  const float* W2     = (const float*)d_in[4];
  const float* b2     = (const float*)d_in[5];
  const float* V1     = (const float*)d_in[6];
  const float* vb1    = (const float*)d_in[7];
  const float* V2     = (const float*)d_in[8];
  const float* vb2    = (const float*)d_in[9];

  char* ws = (char*)d_ws;
  float*          outA  = (float*)(ws + 0);          // 2,000,000 B
  float*          outW  = (float*)(ws + 2000000);    // 2,000,000 B
  float*          sum_o = (float*)(ws + 4000000);    //   100,000 B
  float*          sum_w = (float*)(ws + 4100000);    //   100,000 B
  unsigned short* W1s   = (unsigned short*)(ws + 4200000);  // 204,800 B
  unsigned short* V1s   = (unsigned short*)(ws + 4404800);  // 204,800 B
  float*          b1p   = (float*)(ws + 4609600);    // 1,280 B
  float*          vb1p  = (float*)(ws + 4610880);
  float*          W2p   = (float*)(ws + 4612160);
  float*          V2p   = (float*)(ws + 4613440);

  prep_kernel<<<1001, 256, 0, stream>>>(W1, V1, b1, vb1, W2, V2,
                                        W1s, V1s, b1p, vb1p, W2p, V2p, sum_o);

  const int nblk = (N_ATOMS + BA - 1) / BA;   // 3907
  fused_ffn<<<nblk, 512, 0, stream>>>(hidden, W1s, V1s, b1p, vb1p, W2p, V2p,
                                      b2, vb2, outA, outW);

  segsum_kernel<<<(N_ATOMS / 8 + 255) / 256, 256, 0, stream>>>(outA, outW, seg,
                                                               sum_o, sum_w);

  final_kernel<<<(N_ATOMS / 4 + 255) / 256, 256, 0, stream>>>(outA, outW, seg,
                                                              sum_o, sum_w,
                                                              (float*)d_out);
}

// Round 5
// 418.645 us; speedup vs baseline: 1.5496x; 1.5496x over previous
//
#include <hip/hip_runtime.h>
#include <stdint.h>

#define N_ATOMS 500000
#define N_MOLS  25000
#define HID     300
#define BA      128       // atoms per block
#define WS_ELE  102400    // elements per repacked W matrix (20*10*64*8)

// LDS layout (bytes)
#define AROWB   616               // A row stride: 308 bf16 (304 used); 616%128=104 -> ~2-way banks
#define A_BYTES (BA * AROWB)      // 78,848
#define B_OFF   A_BYTES
#define BUF_B   40960             // one K=32 B chunk: [mtx:2][h:2][nt:10][lane:64][16B]

typedef __attribute__((ext_vector_type(8)))  short          short8v;
typedef __attribute__((ext_vector_type(16))) float          f32x16;

static __device__ __forceinline__ unsigned short f2bf(float f) {
  unsigned int u = __float_as_uint(f);
  u += 0x7fffu + ((u >> 16) & 1u);   // round-to-nearest-even
  return (unsigned short)(u >> 16);
}

// async global->LDS, 16B per lane; lds base wave-uniform.
static __device__ __forceinline__ void stage16(const char* gsrc, char* ldst, int ln) {
  __builtin_amdgcn_global_load_lds(
      (const __attribute__((address_space(1))) void*)(gsrc + ln * 16),
      (__attribute__((address_space(3))) void*)ldst, 16, 0, 0);
}

// ---------------------------------------------------------------------------
// Prep: repack W1/V1 into B-fragment order [kc16:20][nt:10][lane:64][j:8]
// (k = kc16*16 + (lane>>5)*8 + j, n = nt*32 + (lane&31)), pad biases/readout
// vectors to 320, zero the segment-sum accumulators.
// ---------------------------------------------------------------------------
__global__ void prep_kernel(
    const float* __restrict__ W1, const float* __restrict__ V1,
    const float* __restrict__ b1, const float* __restrict__ vb1,
    const float* __restrict__ W2, const float* __restrict__ V2,
    unsigned short* __restrict__ W1s, unsigned short* __restrict__ V1s,
    float* __restrict__ b1p, float* __restrict__ vb1p,
    float* __restrict__ W2p, float* __restrict__ V2p,
    float* __restrict__ sums)
{
  const int t = blockIdx.x * 256 + threadIdx.x;
  if (t < 2 * WS_ELE) {
    const float* src = (t < WS_ELE) ? W1 : V1;
    unsigned short* dst = (t < WS_ELE) ? W1s : V1s;
    const int i    = (t < WS_ELE) ? t : t - WS_ELE;
    const int j    = i & 7;
    const int lane = (i >> 3) & 63;
    const int nt   = (i >> 9) % 10;
    const int kc16 = i / 5120;
    const int k = kc16 * 16 + (lane >> 5) * 8 + j;
    const int n = nt * 32 + (lane & 31);
    const float v = (k < HID && n < HID) ? src[k * HID + n] : 0.f;
    dst[i] = f2bf(v);
  } else if (t < 2 * WS_ELE + 1280) {
    const int i = t - 2 * WS_ELE;
    const int which = i / 320;
    const int e = i - which * 320;
    const float* s = (which == 0) ? b1 : (which == 1) ? vb1 : (which == 2) ? W2 : V2;
    float*       d = (which == 0) ? b1p : (which == 1) ? vb1p : (which == 2) ? W2p : V2p;
    d[e] = (e < HID) ? s[e] : 0.f;
  } else if (t < 2 * WS_ELE + 1280 + 2 * N_MOLS) {
    sums[t - (2 * WS_ELE + 1280)] = 0.f;
  }
}

// ---------------------------------------------------------------------------
// Fused FFN x2. Block = 128 atoms, 512 threads, 8 waves =
// {mtx:2} x {colhalf:2} x {rowhalf:2}; each wave computes 64 atoms x 160 cols
// of ONE matrix (acc = 2x5 f32x16 = 160 regs), so every B-frag LDS read feeds
// 2 MFMAs (chunk is MFMA-bound: 10 MFMA ~80cy vs 7 ds_read_b128 ~60cy).
// A staged ONCE per block, ROW-MAJOR in LDS (stride 616B, ~2-way banks = free)
// in 2 batches of <=10 float4 (no spill). B double-buffered 2x40KB via
// global_load_lds, 2-phase: stage c+1, compute c, one barrier per chunk.
// ---------------------------------------------------------------------------
__global__ __launch_bounds__(512, 2) void fused_ffn(
    const float* __restrict__ hidden,
    const unsigned short* __restrict__ W1s, const unsigned short* __restrict__ V1s,
    const float* __restrict__ b1p, const float* __restrict__ vb1p,
    const float* __restrict__ W2p, const float* __restrict__ V2p,
    const float* __restrict__ b2, const float* __restrict__ vb2,
    float* __restrict__ outA, float* __restrict__ outW)
{
  __shared__ char lds[A_BYTES + 2 * BUF_B];   // 160,768 B
  __shared__ float sOutA[BA];                 // +512
  __shared__ float sOutW[BA];                 // +512  -> 161,792 total

  const int tid = (int)threadIdx.x;
  const int ln  = tid & 63;
  const int wv  = tid >> 6;
  const int mtx = wv & 1;          // 0 = W-pass, 1 = V-pass
  const int ch  = (wv >> 1) & 1;   // col half (160 cols)
  const int rgh = wv >> 2;         // row half (64 atoms)
  const int l31 = ln & 31;
  const int lh  = ln >> 5;
  const long base = (long)blockIdx.x * BA;

  // ---- issue B stage for chunk 0 into buf 0 (before A loads) ----
  {
    char* dst = lds + B_OFF;
    #pragma unroll
    for (int r = 0; r < 5; ++r) {
      const int cc = wv * 5 + r;    // 40 x 1KB pieces: W = 0..19, V = 20..39
      const char* src = (cc < 20) ? ((const char*)W1s + cc * 1024)
                                  : ((const char*)V1s + (cc - 20) * 1024);
      stage16(src, dst + cc * 1024, ln);
    }
  }

  // ---- A: 9728 float4 slots (row = i/76, c4 = i%76; c4==75 -> zero pad) ----
  // two batches (10 + 9 per thread), <=10 float4 live -> no scratch spill
  #pragma unroll
  for (int bt = 0; bt < 2; ++bt) {
    const int nb = bt ? 9 : 10;
    float4 tmp[10];
    #pragma unroll
    for (int m = 0; m < 10; ++m) {
      if (m >= nb) break;
      const int i   = tid + (bt * 10 + m) * 512;
      const int row = i / 76;
      const int c4  = i - row * 76;
      float4 v = make_float4(0.f, 0.f, 0.f, 0.f);
      const long atom = base + row;
      if (c4 < 75 && atom < N_ATOMS)
        v = *reinterpret_cast<const float4*>(hidden + atom * (long)HID + c4 * 4);
      tmp[m] = v;
    }
    #pragma unroll
    for (int m = 0; m < 10; ++m) {
      if (m >= nb) break;
      const int i   = tid + (bt * 10 + m) * 512;
      const int row = i / 76;
      const int c4  = i - row * 76;
      ushort4 b;
      b.x = f2bf(tmp[m].x); b.y = f2bf(tmp[m].y);
      b.z = f2bf(tmp[m].z); b.w = f2bf(tmp[m].w);
      *reinterpret_cast<ushort4*>(lds + row * AROWB + c4 * 8) = b;
    }
  }
  __syncthreads();   // A staged; B chunk 0 landed

  f32x16 acc[2][5] = {};

  // ---- main loop: 10 chunks of K=32 (kc16 = 2c, 2c+1) ----
  for (int c = 0; c < 10; ++c) {
    const char* buf = lds + B_OFF + (c & 1) * BUF_B;

    if (c < 9) {   // stage chunk c+1 into the other buffer
      char* nbuf = lds + B_OFF + ((c + 1) & 1) * BUF_B;
      const char* wsrc = (const char*)W1s + (c + 1) * 20480;
      const char* vsrc = (const char*)V1s + (c + 1) * 20480;
      #pragma unroll
      for (int r = 0; r < 5; ++r) {
        const int cc = wv * 5 + r;
        const char* src = (cc < 20) ? (wsrc + cc * 1024) : (vsrc + (cc - 20) * 1024);
        stage16(src, nbuf + cc * 1024, ln);
      }
    }

    // compute chunk c (skip h=1 at c=9: k in [304,320) has no A region)
#define DO_HALF(hh)                                                            \
    {                                                                          \
      const int kc16 = 2 * c + (hh);                                           \
      const short8v a0 = *reinterpret_cast<const short8v*>(                    \
          lds + (rgh * 64 + l31) * AROWB + kc16 * 32 + lh * 16);               \
      const short8v a1 = *reinterpret_cast<const short8v*>(                    \
          lds + (rgh * 64 + 32 + l31) * AROWB + kc16 * 32 + lh * 16);          \
      const char* bb = buf + mtx * 20480 + (hh) * 10240 + ch * 5120;           \
      _Pragma("unroll")                                                        \
      for (int nt = 0; nt < 5; ++nt) {                                         \
        const short8v bf = *reinterpret_cast<const short8v*>(                  \
            bb + nt * 1024 + ln * 16);                                         \
        acc[0][nt] = __builtin_amdgcn_mfma_f32_32x32x16_bf16(a0, bf, acc[0][nt], 0, 0, 0); \
        acc[1][nt] = __builtin_amdgcn_mfma_f32_32x32x16_bf16(a1, bf, acc[1][nt], 0, 0, 0); \
      }                                                                        \
    }
    DO_HALF(0);
    if (c < 9) DO_HALF(1);
#undef DO_HALF

    __syncthreads();
  }

  // ---- epilogue: out[atom] = sum_n relu(X+b1)*W2 + b2 ----
  float bv[5], w2[5];
  const float* bbv = mtx ? vb1p : b1p;
  const float* ww2 = mtx ? V2p  : W2p;
  #pragma unroll
  for (int nt = 0; nt < 5; ++nt) {
    const int cix = ch * 160 + nt * 32 + l31;
    bv[nt] = bbv[cix];
    w2[nt] = ww2[cix];
  }
  if (tid < BA) { sOutA[tid] = 0.f; sOutW[tid] = 0.f; }
  __syncthreads();

  float* sOut = mtx ? sOutW : sOutA;
  #pragma unroll
  for (int rg = 0; rg < 2; ++rg) {
    #pragma unroll
    for (int r = 0; r < 16; ++r) {
      float s = 0.f;
      #pragma unroll
      for (int nt = 0; nt < 5; ++nt) {
        float x = fmaxf(acc[rg][nt][r] + bv[nt], 0.f);
        s = fmaf(x, w2[nt], s);
      }
      s += __shfl_xor(s, 1);
      s += __shfl_xor(s, 2);
      s += __shfl_xor(s, 4);
      s += __shfl_xor(s, 8);
      s += __shfl_xor(s, 16);
      if (l31 == 0) {
        const int row = rgh * 64 + rg * 32 + (r & 3) + 8 * (r >> 2) + 4 * lh;
        atomicAdd(&sOut[row], s);
      }
    }
  }
  __syncthreads();
  if (tid < BA) {
    const long atom = base + tid;
    if (atom < N_ATOMS) {
      outA[atom] = sOutA[tid] + b2[0];
      outW[atom] = sOutW[tid] + vb2[0];
    }
  }
}

// ---------------------------------------------------------------------------
// Segment sums: sorted seg_ids, run-compress 8 atoms/thread before atomics.
// ---------------------------------------------------------------------------
__global__ void segsum_kernel(
    const float* __restrict__ outA, const float* __restrict__ outW,
    const int* __restrict__ seg,
    float* __restrict__ sum_o, float* __restrict__ sum_w)
{
  const long i0 = ((long)blockIdx.x * 256 + threadIdx.x) * 8;
  if (i0 >= N_ATOMS) return;
  const int4   s0 = *reinterpret_cast<const int4*>(seg + i0);
  const int4   s1 = *reinterpret_cast<const int4*>(seg + i0 + 4);
  const float4 o0 = *reinterpret_cast<const float4*>(outA + i0);
  const float4 o1 = *reinterpret_cast<const float4*>(outA + i0 + 4);
  const float4 w0 = *reinterpret_cast<const float4*>(outW + i0);
  const float4 w1 = *reinterpret_cast<const float4*>(outW + i0 + 4);
  const int   ss[8] = {s0.x, s0.y, s0.z, s0.w, s1.x, s1.y, s1.z, s1.w};
  const float oo[8] = {o0.x, o0.y, o0.z, o0.w, o1.x, o1.y, o1.z, o1.w};
  const float ww[8] = {w0.x, w0.y, w0.z, w0.w, w1.x, w1.y, w1.z, w1.w};
  int cur = ss[0];
  float ao = 0.f, aw = 0.f;
  #pragma unroll
  for (int j = 0; j < 8; ++j) {
    if (ss[j] != cur) {
      atomicAdd(&sum_o[cur], ao);
      atomicAdd(&sum_w[cur], aw);
      cur = ss[j]; ao = 0.f; aw = 0.f;
    }
    ao += oo[j]; aw += ww[j];
  }
  atomicAdd(&sum_o[cur], ao);
  atomicAdd(&sum_w[cur], aw);
}

// ---------------------------------------------------------------------------
// Final: out = output + weights * (0 - sum_o[seg]) / sum_w'[seg]
// ---------------------------------------------------------------------------
__global__ void final_kernel(
    const float* __restrict__ outA, const float* __restrict__ outW,
    const int* __restrict__ seg,
    const float* __restrict__ sum_o, const float* __restrict__ sum_w,
    float* __restrict__ out)
{
  const long i0 = ((long)blockIdx.x * 256 + threadIdx.x) * 4;
  if (i0 >= N_ATOMS) return;
  const int4   s4 = *reinterpret_cast<const int4*>(seg + i0);
  const float4 o4 = *reinterpret_cast<const float4*>(outA + i0);
  const float4 w4 = *reinterpret_cast<const float4*>(outW + i0);
  const int   ss[4] = {s4.x, s4.y, s4.z, s4.w};
  const float oo[4] = {o4.x, o4.y, o4.z, o4.w};
  const float ww[4] = {w4.x, w4.y, w4.z, w4.w};
  float r[4];
  #pragma unroll
  for (int j = 0; j < 4; ++j) {
    const int s = ss[j];
    float sw = sum_w[s];
    sw = (sw == 0.f) ? 1.f : sw;
    const float corr = (0.f - sum_o[s]) / sw;
    r[j] = oo[j] + ww[j] * corr;
  }
  *reinterpret_cast<float4*>(out + i0) = make_float4(r[0], r[1], r[2], r[3]);
}

// ---------------------------------------------------------------------------
extern "C" void kernel_launch(void* const* d_in, const int* in_sizes, int n_in,
                              void* d_out, int out_size, void* d_ws, size_t ws_size,
                              hipStream_t stream)
{
  const float* hidden = (const float*)d_in[0];
  const int*   seg    = (const int*)d_in[1];
  const float* W1     = (const float*)d_in[2];
  const float* b1     = (const float*)d_in[3];
  const float* W2     = (const float*)d_in[4];
  const float* b2     = (const float*)d_in[5];
  const float* V1     = (const float*)d_in[6];
  const float* vb1    = (const float*)d_in[7];
  const float* V2     = (const float*)d_in[8];
  const float* vb2    = (const float*)d_in[9];

  char* ws = (char*)d_ws;
  float*          outA  = (float*)(ws + 0);          // 2,000,000 B
  float*          outW  = (float*)(ws + 2000000);    // 2,000,000 B
  float*          sum_o = (float*)(ws + 4000000);    //   100,000 B
  float*          sum_w = (float*)(ws + 4100000);    //   100,000 B
  unsigned short* W1s   = (unsigned short*)(ws + 4200000);  // 204,800 B
  unsigned short* V1s   = (unsigned short*)(ws + 4404800);  // 204,800 B
  float*          b1p   = (float*)(ws + 4609600);    // 1,280 B
  float*          vb1p  = (float*)(ws + 4610880);
  float*          W2p   = (float*)(ws + 4612160);
  float*          V2p   = (float*)(ws + 4613440);

  prep_kernel<<<1001, 256, 0, stream>>>(W1, V1, b1, vb1, W2, V2,
                                        W1s, V1s, b1p, vb1p, W2p, V2p, sum_o);

  const int nblk = (N_ATOMS + BA - 1) / BA;   // 3907
  fused_ffn<<<nblk, 512, 0, stream>>>(hidden, W1s, V1s, b1p, vb1p, W2p, V2p,
                                      b2, vb2, outA, outW);

  segsum_kernel<<<(N_ATOMS / 8 + 255) / 256, 256, 0, stream>>>(outA, outW, seg,
                                                               sum_o, sum_w);

  final_kernel<<<(N_ATOMS / 4 + 255) / 256, 256, 0, stream>>>(outA, outW, seg,
                                                              sum_o, sum_w,
                                                              (float*)d_out);
}